// Round 3
// baseline (450.019 us; speedup 1.0000x reference)
//
#include <hip/hip_runtime.h>
#include <math.h>

#define C_DIM 128
#define SHD   16
#define HID   128
#define MIN_D 64
#define OUT_PER_NODE 2048   // C * (1+3+5+7)
#define BLK   256
#define SCAN_T 1024
#define G     4             // dst nodes per conv block

typedef __attribute__((ext_vector_type(8))) short bf16x8;
typedef __attribute__((ext_vector_type(4))) float f32x4;

__device__ __forceinline__ unsigned f2bf_u(float x) {
    unsigned u = __builtin_bit_cast(unsigned, x);
    return (u + 0x7fffu + ((u >> 16) & 1u)) >> 16;   // round-to-nearest-even
}
__device__ __forceinline__ short f2bf(float x) { return (short)f2bf_u(x); }
__device__ __forceinline__ unsigned packbf2(float a, float b) {
    return f2bf_u(a) | (f2bf_u(b) << 16);
}
__device__ __forceinline__ float bf2f(unsigned h) {
    return __builtin_bit_cast(float, h << 16);
}

// ---------------- prep: histogram + weight conversion (fused) ----------------
// w2t column permutation: wave w / tile j / lane m16 owns output channel
// 128*w + 8*m16 + j (j=0..7), so layer-2 transpose store is one uint4 per lane.
__global__ void prep_kernel(const int* __restrict__ dst, int* counts, int E,
                            const float* __restrict__ W1, const float* __restrict__ W2,
                            short* __restrict__ w1t, short* __restrict__ w2t,
                            int HB) {
    int b = blockIdx.x;
    int t = threadIdx.x;
    if (b < HB) {
        int i = b * BLK + t;
        if (i < E) atomicAdd(&counts[dst[i]], 1);
    } else {
        int i = (b - HB) * BLK + t;
        if (i < MIN_D * HID) {
            int n = i >> 6, k = i & 63;
            w1t[i] = f2bf(W1[k * HID + n] * 0.125f);
        } else if (i < MIN_D * HID + HID * 512) {
            int j = i - MIN_D * HID;
            int p = j >> 7, ks = j & 127;
            int nt = p >> 4, m16 = p & 15;
            int jcol = 128 * (nt >> 3) + 8 * m16 + (nt & 7);   // wave-section mapping
            int ka   = (2 * (ks >> 5) + (ks & 1)) * 16 + ((ks >> 1) & 15);
            w2t[j] = f2bf(W2[ka * 512 + jcol] * 0.0883883476483184f);
        }
    }
}

__global__ __launch_bounds__(SCAN_T)
void scan_kernel(const int* __restrict__ counts, int* row_ptr, int* cursor, int n) {
    const int t = threadIdx.x;
    const int per = (n + SCAN_T - 1) / SCAN_T;
    int lp[16];
    int base = t * per;
    int sum = 0;
    for (int i = 0; i < per && i < 16; ++i) {
        int idx = base + i;
        int v = (idx < n) ? counts[idx] : 0;
        lp[i] = sum;
        sum += v;
    }
    __shared__ int sbuf[SCAN_T];
    sbuf[t] = sum;
    __syncthreads();
    for (int off = 1; off < SCAN_T; off <<= 1) {
        int v = (t >= off) ? sbuf[t - off] : 0;
        __syncthreads();
        sbuf[t] += v;
        __syncthreads();
    }
    int excl = (t == 0) ? 0 : sbuf[t - 1];
    for (int i = 0; i < per && i < 16; ++i) {
        int idx = base + i;
        if (idx < n) {
            int rp = excl + lp[i];
            row_ptr[idx] = rp;
            cursor[idx]  = rp;
        }
    }
    if (t == SCAN_T - 1) row_ptr[n] = sbuf[SCAN_T - 1];
}

__global__ void scatter_kernel(const int* __restrict__ dst, const int* __restrict__ src,
                               int* cursor, int2* es_list, int E) {
    int i = blockIdx.x * blockDim.x + threadIdx.x;
    if (i < E) {
        int pos = atomicAdd(&cursor[dst[i]], 1);
        es_list[pos] = make_int2(i, src[i]);
    }
}

// ---------------- TP walk helpers (barrier-free, templated by l) -------------
template<int L>
__device__ __forceinline__ void tp_chunk(
    const float* __restrict__ src_features,
    const float* __restrict__ edge_sh,
    const unsigned* tp_lds,
    const int2* __restrict__ es_list,
    const int* __restrict__ row_ptr,
    float* __restrict__ out,
    float* accA, float* accB, int& g, int& nextb,
    int p0, int cnt, int n0, int n_valid, int tq)
{
    constexpr int D = 2 * L + 1;
    constexpr int SHOFF = L * L;
    const int c0 = (2 * tq) & 127;
    int i = p0;
    const int pend = p0 + cnt;
    while (i < pend && g < n_valid) {
        const int e = (nextb < pend) ? nextb : pend;
        int il = i - p0;
        while (i + 4 <= e) {
            int2 es[4];
#pragma unroll
            for (int k = 0; k < 4; ++k) es[k] = es_list[i + k];
            unsigned tp2[4]; float2 x[4]; float sh[4][D];
#pragma unroll
            for (int k = 0; k < 4; ++k) {
                tp2[k] = tp_lds[(il + k) * 256 + tq];
                x[k]   = *(const float2*)&src_features[(size_t)es[k].y * C_DIM + c0];
                const float* shp = &edge_sh[(size_t)es[k].x * SHD + SHOFF];
#pragma unroll
                for (int m = 0; m < D; ++m) sh[k][m] = shp[m];
            }
#pragma unroll
            for (int k = 0; k < 4; ++k) {
                float wx0 = bf2f(tp2[k] & 0xffffu) * x[k].x;
                float wx1 = bf2f(tp2[k] >> 16)     * x[k].y;
#pragma unroll
                for (int m = 0; m < D; ++m) {
                    accA[m] += wx0 * sh[k][m];
                    accB[m] += wx1 * sh[k][m];
                }
            }
            i += 4; il += 4;
        }
        while (i < e) {
            int2 es = es_list[i];
            unsigned tp2 = tp_lds[il * 256 + tq];
            float2 x = *(const float2*)&src_features[(size_t)es.y * C_DIM + c0];
            const float* shp = &edge_sh[(size_t)es.x * SHD + SHOFF];
            float wx0 = bf2f(tp2 & 0xffffu) * x.x;
            float wx1 = bf2f(tp2 >> 16)     * x.y;
#pragma unroll
            for (int m = 0; m < D; ++m) {
                float shv = shp[m];
                accA[m] += wx0 * shv;
                accB[m] += wx1 * shv;
            }
            ++i; ++il;
        }
        if (i == nextb) {   // node n0+g complete -> plain store (block owns it)
            float* op = out + (size_t)(n0 + g) * OUT_PER_NODE + 128 * SHOFF + c0 * D;
#pragma unroll
            for (int m = 0; m < D; ++m) op[m] = accA[m];
#pragma unroll
            for (int m = 0; m < D; ++m) op[D + m] = accB[m];
#pragma unroll
            for (int m = 0; m < D; ++m) { accA[m] = 0.f; accB[m] = 0.f; }
            ++g;
            nextb = (g < n_valid) ? row_ptr[n0 + g + 1] : 0x7fffffff;
        }
    }
}

template<int L>
__device__ __forceinline__ void tp_flush(
    float* __restrict__ out, float* accA, float* accB,
    int& g, int n_valid, int n0, int tq)
{
    constexpr int D = 2 * L + 1;
    constexpr int SHOFF = L * L;
    const int c0 = (2 * tq) & 127;
    while (g < n_valid) {   // trailing empty nodes (acc already zero)
        float* op = out + (size_t)(n0 + g) * OUT_PER_NODE + 128 * SHOFF + c0 * D;
#pragma unroll
        for (int m = 0; m < D; ++m) op[m] = accA[m];
#pragma unroll
        for (int m = 0; m < D; ++m) op[D + m] = accB[m];
#pragma unroll
        for (int m = 0; m < D; ++m) { accA[m] = 0.f; accB[m] = 0.f; }
        ++g;
    }
}

// ---------------- fused conv: MLP(L1+L2) + TP + segment-sum, node-centric ----
// Block = G=4 whole dst nodes (edges contiguous in es_list). Per 16-edge chunk:
//   L1: gather emb rows -> MFMA (W1 frags hoisted) -> hb LDS (4KB, XOR-swz)
//   L2: hb -> 32 MFMA, W2 streamed from L2 -> tp_lds (16KB, wave-private section)
//   TP: walk chunk edges, uniform segment boundaries, plain out stores.
// No atomics, no out intermediate. LDS 20KB; barriers uniform (2/chunk).
__global__ __launch_bounds__(BLK, 4)
void conv_kernel(const float* __restrict__ edge_emb,
                 const short* __restrict__ w1t,
                 const short* __restrict__ w2t,
                 const float* __restrict__ src_features,
                 const float* __restrict__ edge_sh,
                 const int* __restrict__ row_ptr,
                 const int2* __restrict__ es_list,
                 float* __restrict__ out,
                 int n_dst)
{
    const int t    = threadIdx.x;
    const int lane = t & 63;
    const int wv   = t >> 6;        // wave 0..3 == harmonic l == col-section
    const int m16  = lane & 15;
    const int q    = lane >> 4;

    const int n0      = blockIdx.x * G;
    const int n_valid = (n_dst - n0 < G) ? (n_dst - n0) : G;
    const int rbeg    = row_ptr[n0];
    const int rend    = row_ptr[n0 + n_valid];
    const int nch     = (rend - rbeg + 15) >> 4;

    __shared__ __align__(16) unsigned tp_lds[16 * 256];  // 16 KB
    __shared__ __align__(16) unsigned hb[1024];          // 4 KB, XOR-swizzled

    union CVT { unsigned u[4]; bf16x8 v; };

    // hoisted layer-1 B-frags (w1t is L1-resident): n-tiles 2wv, 2wv+1
    bf16x8 b1a[2], b1b[2];
#pragma unroll
    for (int ks = 0; ks < 2; ++ks) {
        b1a[ks] = *(const bf16x8*)&w1t[((2 * wv)     * 16 + m16) * MIN_D + ks * 32 + q * 8];
        b1b[ks] = *(const bf16x8*)&w1t[((2 * wv + 1) * 16 + m16) * MIN_D + ks * 32 + q * 8];
    }

    float accA[7], accB[7];
#pragma unroll
    for (int m = 0; m < 7; ++m) { accA[m] = 0.f; accB[m] = 0.f; }
    int g     = 0;
    int nextb = row_ptr[n0 + 1];

    for (int c = 0; c < nch; ++c) {
        const int p0  = rbeg + (c << 4);
        const int cnt = (rend - p0 < 16) ? (rend - p0) : 16;

        // ---- layer 1: 16 edges x 128 hidden ----
        bf16x8 a[2];
        if (m16 < cnt) {
            const int eid = es_list[p0 + m16].x;
            const float* rp = &edge_emb[(size_t)eid * MIN_D];
#pragma unroll
            for (int ks = 0; ks < 2; ++ks) {
                float4 v0 = *(const float4*)&rp[ks * 32 + q * 8];
                float4 v1 = *(const float4*)&rp[ks * 32 + q * 8 + 4];
                CVT cc;
                cc.u[0] = packbf2(v0.x, v0.y);
                cc.u[1] = packbf2(v0.z, v0.w);
                cc.u[2] = packbf2(v1.x, v1.y);
                cc.u[3] = packbf2(v1.z, v1.w);
                a[ks] = cc.v;
            }
        } else {
            CVT cc; cc.u[0] = cc.u[1] = cc.u[2] = cc.u[3] = 0u;
            a[0] = cc.v; a[1] = cc.v;
        }
        f32x4 h0 = {0.f, 0.f, 0.f, 0.f}, h1 = {0.f, 0.f, 0.f, 0.f};
#pragma unroll
        for (int ks = 0; ks < 2; ++ks) {
            h0 = __builtin_amdgcn_mfma_f32_16x16x32_bf16(a[ks], b1a[ks], h0, 0, 0, 0);
            h1 = __builtin_amdgcn_mfma_f32_16x16x32_bf16(a[ks], b1b[ks], h1, 0, 0, 0);
        }
#pragma unroll
        for (int r = 0; r < 4; ++r) {
            const int row = q * 4 + r;
            float z0 = h0[r], z1 = h1[r];
            float s0 = z0 / (1.f + __expf(-z0));
            float s1 = z1 / (1.f + __expf(-z1));
            // dword d=16wv+m16 holds hidden pair (32wv+m16, +16); XOR swizzle on
            // bits 2..4 keeps b128 groups intact, kills stride-256B conflicts
            hb[(row * 64 + 16 * wv + m16) ^ ((row & 7) << 2)] = packbf2(s0, s1);
        }
        __syncthreads();

        // ---- layer 2: h(16x128) @ W2(128x512) -> tp_lds ----
        {
            bf16x8 av[4];
#pragma unroll
            for (int ks = 0; ks < 4; ++ks)
                av[ks] = *(const bf16x8*)&hb[(m16 * 64 + ks * 16 + q * 4) ^ ((m16 & 7) << 2)];
            f32x4 p[8];
#pragma unroll
            for (int j = 0; j < 8; ++j) p[j] = (f32x4){0.f, 0.f, 0.f, 0.f};
#pragma unroll
            for (int ks = 0; ks < 4; ++ks)
#pragma unroll
                for (int j = 0; j < 8; ++j) {
                    bf16x8 B = *(const bf16x8*)&w2t[((8 * wv + j) * 16 + m16) * HID + ks * 32 + q * 8];
                    p[j] = __builtin_amdgcn_mfma_f32_16x16x32_bf16(av[ks], B, p[j], 0, 0, 0);
                }
            // acc[j][r] = tp_w[edge row=4q+r][channel 128wv + 8*m16 + j]
            // -> dwords 64wv+4m16 .. +3 (uint4), matching tp dword semantics
            //    d: l=d>>6, channel pair 2*(d&63)
#pragma unroll
            for (int r = 0; r < 4; ++r) {
                uint4 u;
                u.x = packbf2(p[0][r], p[1][r]);
                u.y = packbf2(p[2][r], p[3][r]);
                u.z = packbf2(p[4][r], p[5][r]);
                u.w = packbf2(p[6][r], p[7][r]);
                *(uint4*)&tp_lds[(q * 4 + r) * 256 + 64 * wv + 4 * m16] = u;
            }
        }

        // tp_lds section [64wv, 64wv+63] is written & read by the SAME wave ->
        // same-wave RAW handled by lgkmcnt; no barrier before the TP walk.
        if (wv == 0)      tp_chunk<0>(src_features, edge_sh, tp_lds, es_list, row_ptr, out, accA, accB, g, nextb, p0, cnt, n0, n_valid, t);
        else if (wv == 1) tp_chunk<1>(src_features, edge_sh, tp_lds, es_list, row_ptr, out, accA, accB, g, nextb, p0, cnt, n0, n_valid, t);
        else if (wv == 2) tp_chunk<2>(src_features, edge_sh, tp_lds, es_list, row_ptr, out, accA, accB, g, nextb, p0, cnt, n0, n_valid, t);
        else              tp_chunk<3>(src_features, edge_sh, tp_lds, es_list, row_ptr, out, accA, accB, g, nextb, p0, cnt, n0, n_valid, t);

        __syncthreads();   // hb WAR: all waves done reading before next L1 stores
    }

    // trailing empty nodes (or nch==0): store zeros
    if (wv == 0)      tp_flush<0>(out, accA, accB, g, n_valid, n0, t);
    else if (wv == 1) tp_flush<1>(out, accA, accB, g, n_valid, n0, t);
    else if (wv == 2) tp_flush<2>(out, accA, accB, g, n_valid, n0, t);
    else              tp_flush<3>(out, accA, accB, g, n_valid, n0, t);
}

// ---------------- launch ----------------
extern "C" void kernel_launch(void* const* d_in, const int* in_sizes, int n_in,
                              void* d_out, int out_size, void* d_ws, size_t ws_size,
                              hipStream_t stream) {
    const float* src_features = (const float*)d_in[0];
    const float* edge_sh      = (const float*)d_in[1];
    const float* edge_emb     = (const float*)d_in[2];
    const float* W1           = (const float*)d_in[3];
    const float* W2           = (const float*)d_in[4];
    const int*   src          = (const int*)d_in[5];
    const int*   dst          = (const int*)d_in[6];

    const int E     = in_sizes[5];
    const int N_DST = out_size / OUT_PER_NODE;
    const int NBC   = (N_DST + G - 1) / G;

    // ws layout (16B-aligned pieces first)
    char* p = (char*)d_ws;
    short* w1t    = (short*)p;  p += MIN_D * HID * 2;   // 16 KB
    short* w2t    = (short*)p;  p += HID * 512 * 2;     // 128 KB
    int2* es_list = (int2*)p;   p += (size_t)E * 8;
    int* counts   = (int*)p;    p += 16384 * 4;
    int* row_ptr  = (int*)p;    p += 16384 * 4;
    int* cursor   = (int*)p;    p += 16384 * 4;

    const int HB = (E + BLK - 1) / BLK;
    const int CB = (MIN_D * HID + HID * 512 + BLK - 1) / BLK;

    (void)hipMemsetAsync(counts, 0, (size_t)N_DST * 4, stream);
    prep_kernel<<<HB + CB, BLK, 0, stream>>>(dst, counts, E, W1, W2, w1t, w2t, HB);
    scan_kernel<<<1, SCAN_T, 0, stream>>>(counts, row_ptr, cursor, N_DST);
    scatter_kernel<<<(E + 255) / 256, 256, 0, stream>>>(dst, src, cursor, es_list, E);
    conv_kernel<<<NBC, BLK, 0, stream>>>(edge_emb, w1t, w2t, src_features, edge_sh,
                                         row_ptr, es_list, (float*)d_out, N_DST);
}

// Round 4
// 229.308 us; speedup vs baseline: 1.9625x; 1.9625x over previous
//
#include <hip/hip_runtime.h>
#include <math.h>

#define C_DIM 128
#define SHD   16
#define HID   128
#define MIN_D 64
#define OUT_PER_NODE 2048   // C * (1+3+5+7)
#define BLK   256
#define MBLK  512           // mlp block (8 waves)
#define SCAN_T 1024
#define MT    128           // edges per MLP block

// LDS row stride (shorts), 16B-aligned rows
#define HST 136   // h stride (128+8) -> 272 B

typedef __attribute__((ext_vector_type(8))) short bf16x8;
typedef __attribute__((ext_vector_type(4))) float f32x4;

__device__ __forceinline__ unsigned f2bf_u(float x) {
    unsigned u = __builtin_bit_cast(unsigned, x);
    return (u + 0x7fffu + ((u >> 16) & 1u)) >> 16;   // round-to-nearest-even
}
__device__ __forceinline__ short f2bf(float x) { return (short)f2bf_u(x); }
__device__ __forceinline__ unsigned packbf2(float a, float b) {
    return f2bf_u(a) | (f2bf_u(b) << 16);
}
__device__ __forceinline__ float bf2f(unsigned h) {
    return __builtin_bit_cast(float, h << 16);
}

// ---------------- prep: histogram + weight conversion (fused) ----------------
// jcol mapping (R2-verified): wave w / tile j / lane m16 owns output channel
// 64*w + 4*m16 + j, so Phase B stores one contiguous uint2 per lane.
__global__ void prep_kernel(const int* __restrict__ dst, int* counts, int E,
                            const float* __restrict__ W1, const float* __restrict__ W2,
                            short* __restrict__ w1t, short* __restrict__ w2t,
                            int HB) {
    int b = blockIdx.x;
    int t = threadIdx.x;
    if (b < HB) {
        int i = b * BLK + t;
        if (i < E) atomicAdd(&counts[dst[i]], 1);
    } else {
        int i = (b - HB) * BLK + t;
        if (i < MIN_D * HID) {
            int n = i >> 6, k = i & 63;
            w1t[i] = f2bf(W1[k * HID + n] * 0.125f);
        } else if (i < MIN_D * HID + HID * 512) {
            int j = i - MIN_D * HID;
            int p = j >> 7, ks = j & 127;
            int nt = p >> 4, m16 = p & 15;
            int jcol = 64 * (nt >> 2) + 4 * m16 + (nt & 3);   // R2-verified mapping
            int ka   = (2 * (ks >> 5) + (ks & 1)) * 16 + ((ks >> 1) & 15);
            w2t[j] = f2bf(W2[ka * 512 + jcol] * 0.0883883476483184f);
        }
    }
}

__global__ __launch_bounds__(SCAN_T)
void scan_kernel(const int* __restrict__ counts, int* row_ptr, int* cursor, int n) {
    const int t = threadIdx.x;
    const int per = (n + SCAN_T - 1) / SCAN_T;
    int lp[16];
    int base = t * per;
    int sum = 0;
    for (int i = 0; i < per && i < 16; ++i) {
        int idx = base + i;
        int v = (idx < n) ? counts[idx] : 0;
        lp[i] = sum;
        sum += v;
    }
    __shared__ int sbuf[SCAN_T];
    sbuf[t] = sum;
    __syncthreads();
    for (int off = 1; off < SCAN_T; off <<= 1) {
        int v = (t >= off) ? sbuf[t - off] : 0;
        __syncthreads();
        sbuf[t] += v;
        __syncthreads();
    }
    int excl = (t == 0) ? 0 : sbuf[t - 1];
    for (int i = 0; i < per && i < 16; ++i) {
        int idx = base + i;
        if (idx < n) {
            int rp = excl + lp[i];
            row_ptr[idx] = rp;
            cursor[idx]  = rp;
        }
    }
    if (t == SCAN_T - 1) row_ptr[n] = sbuf[SCAN_T - 1];
}

__global__ void scatter_kernel(const int* __restrict__ dst, const int* __restrict__ src,
                               int* cursor, int2* es_list, int E) {
    int i = blockIdx.x * blockDim.x + threadIdx.x;
    if (i < E) {
        int pos = atomicAdd(&cursor[dst[i]], 1);
        es_list[pos] = make_int2(i, src[i]);
    }
}

// ---------------- kernel 1: edge-parallel fused MLP ----------------
// 8 waves. Phase A: wave w computes m-tile w (16 edges) x all 128 h-cols,
// A-frags direct from global. Phase B: wave w owns n-tiles 4w..4w+3 (B in
// registers, loaded pre-barrier), loops all 8 m-tiles from LDS h.
__global__ __launch_bounds__(MBLK)
void mlp_kernel(const float* __restrict__ edge_emb,
                const short* __restrict__ w1t,
                const short* __restrict__ w2t,
                unsigned* __restrict__ tp_u,   // E x 256 dwords
                int E)
{
    const int t    = threadIdx.x;
    const int lane = t & 63;
    const int w    = t >> 6;        // 0..7
    const int m16  = lane & 15;
    const int q    = lane >> 4;
    const int e0   = blockIdx.x * MT;

    __shared__ __align__(16) short hb[MT * HST];
    unsigned* hb_u = (unsigned*)hb;

    union CVT { unsigned u[4]; bf16x8 v; };

    // ---- Phase A: A-frags for m-tile w, direct from global ----
    bf16x8 a[2];
    {
        const int row = e0 + w * 16 + m16;
        if (row < E) {
            const float* rp = &edge_emb[(size_t)row * MIN_D];
#pragma unroll
            for (int ks = 0; ks < 2; ++ks) {
                float4 v0 = *(const float4*)&rp[ks * 32 + q * 8];
                float4 v1 = *(const float4*)&rp[ks * 32 + q * 8 + 4];
                CVT c;
                c.u[0] = packbf2(v0.x, v0.y);
                c.u[1] = packbf2(v0.z, v0.w);
                c.u[2] = packbf2(v1.x, v1.y);
                c.u[3] = packbf2(v1.z, v1.w);
                a[ks] = c.v;
            }
        } else {
            CVT c; c.u[0] = c.u[1] = c.u[2] = c.u[3] = 0u;
            a[0] = c.v; a[1] = c.v;
        }
    }

#pragma unroll
    for (int u2 = 0; u2 < 4; ++u2) {
        f32x4 c0 = {0.f, 0.f, 0.f, 0.f}, c1 = {0.f, 0.f, 0.f, 0.f};
#pragma unroll
        for (int ks = 0; ks < 2; ++ks) {
            bf16x8 b0 = *(const bf16x8*)&w1t[((2 * u2) * 16 + m16) * MIN_D + ks * 32 + q * 8];
            bf16x8 b1 = *(const bf16x8*)&w1t[((2 * u2 + 1) * 16 + m16) * MIN_D + ks * 32 + q * 8];
            c0 = __builtin_amdgcn_mfma_f32_16x16x32_bf16(a[ks], b0, c0, 0, 0, 0);
            c1 = __builtin_amdgcn_mfma_f32_16x16x32_bf16(a[ks], b1, c1, 0, 0, 0);
        }
#pragma unroll
        for (int r = 0; r < 4; ++r) {
            int hrow = w * 16 + q * 4 + r;
            float z0 = c0[r], z1 = c1[r];
            float h0 = z0 / (1.f + __expf(-z0));
            float h1 = z1 / (1.f + __expf(-z1));
            hb_u[hrow * (HST / 2) + 16 * u2 + m16] = packbf2(h0, h1);
        }
    }

    // ---- load Phase-B B-frags BEFORE barrier (overlaps other waves' Phase A) ----
    bf16x8 B[4][4];
#pragma unroll
    for (int j = 0; j < 4; ++j)
#pragma unroll
        for (int ks = 0; ks < 4; ++ks)
            B[j][ks] = *(const bf16x8*)&w2t[((4 * w + j) * 16 + m16) * HID + ks * 32 + q * 8];

    __syncthreads();

    // ---- Phase B: loop all 8 m-tiles; 16 MFMAs each; uint2 coalesced stores ----
    // acc[j][r] = tp_w[edge row][channel 64w + 4*m16 + j]  (new jcol mapping)
    // -> dwords 32w + 2*m16 + {0,1}; dword d holds global channels {2d, 2d+1},
    //    identical semantics to the old per-dword layout consumed by tp_kernel.
    const int d0 = 32 * w + 2 * m16;
    for (int mt = 0; mt < 8; ++mt) {
        bf16x8 av[4];
#pragma unroll
        for (int ks = 0; ks < 4; ++ks)
            av[ks] = *(const bf16x8*)&hb[(mt * 16 + m16) * HST + ks * 32 + q * 8];
        f32x4 acc[4];
#pragma unroll
        for (int j = 0; j < 4; ++j) acc[j] = (f32x4){0.f, 0.f, 0.f, 0.f};
#pragma unroll
        for (int ks = 0; ks < 4; ++ks)
#pragma unroll
            for (int j = 0; j < 4; ++j)
                acc[j] = __builtin_amdgcn_mfma_f32_16x16x32_bf16(av[ks], B[j][ks], acc[j], 0, 0, 0);
#pragma unroll
        for (int r = 0; r < 4; ++r) {
            int e = e0 + mt * 16 + q * 4 + r;
            if (e < E) {
                uint2 u;
                u.x = packbf2(acc[0][r], acc[1][r]);   // channels 64w+4m16, +1
                u.y = packbf2(acc[2][r], acc[3][r]);   // channels 64w+4m16+2, +3
                *(uint2*)&tp_u[(size_t)e * 256 + d0] = u;
            }
        }
    }
}

// ---------------- kernel 2: tensor-product + segment-sum ----------------
template<int L>
__device__ __forceinline__ void tp_node(
    const float* __restrict__ src_features,
    const float* __restrict__ edge_sh,
    const unsigned* __restrict__ tp_u,
    const int2* __restrict__ es_list,
    float* __restrict__ out,
    int n, int t, int rbeg, int rend)
{
    constexpr int D = 2 * L + 1;
    constexpr int SHOFF = L * L;
    const int c0 = (2 * t) & 127;
    const int obase = 128 * L * L + c0 * D;

    float accA[D], accB[D];
#pragma unroll
    for (int m = 0; m < D; ++m) { accA[m] = 0.f; accB[m] = 0.f; }

    int i = rbeg;
    for (; i + 4 <= rend; i += 4) {
        int2 es[4];
#pragma unroll
        for (int k = 0; k < 4; ++k) es[k] = es_list[i + k];
        unsigned tp2[4]; float2 x[4]; float sh[4][D];
#pragma unroll
        for (int k = 0; k < 4; ++k) {
            tp2[k] = tp_u[(size_t)es[k].x * 256 + t];
            x[k]   = *(const float2*)&src_features[(size_t)es[k].y * C_DIM + c0];
            const float* shp = &edge_sh[(size_t)es[k].x * SHD + SHOFF];
#pragma unroll
            for (int m = 0; m < D; ++m) sh[k][m] = shp[m];
        }
#pragma unroll
        for (int k = 0; k < 4; ++k) {
            float wx0 = bf2f(tp2[k] & 0xffffu) * x[k].x;
            float wx1 = bf2f(tp2[k] >> 16)     * x[k].y;
#pragma unroll
            for (int m = 0; m < D; ++m) {
                accA[m] += wx0 * sh[k][m];
                accB[m] += wx1 * sh[k][m];
            }
        }
    }
    for (; i < rend; ++i) {
        int2 es = es_list[i];
        unsigned tp2 = tp_u[(size_t)es.x * 256 + t];
        float2 x = *(const float2*)&src_features[(size_t)es.y * C_DIM + c0];
        float wx0 = bf2f(tp2 & 0xffffu) * x.x;
        float wx1 = bf2f(tp2 >> 16)     * x.y;
        const float* shp = &edge_sh[(size_t)es.x * SHD + SHOFF];
#pragma unroll
        for (int m = 0; m < D; ++m) {
            float sh = shp[m];
            accA[m] += wx0 * sh;
            accB[m] += wx1 * sh;
        }
    }

    float* op = out + (size_t)n * OUT_PER_NODE + obase;
#pragma unroll
    for (int m = 0; m < D; ++m) op[m] = accA[m];
#pragma unroll
    for (int m = 0; m < D; ++m) op[D + m] = accB[m];
}

__global__ __launch_bounds__(BLK)
void tp_kernel(const float* __restrict__ src_features,
               const float* __restrict__ edge_sh,
               const unsigned* __restrict__ tp_u,
               const int* __restrict__ row_ptr,
               const int2* __restrict__ es_list,
               float* __restrict__ out)
{
    const int n = blockIdx.x;
    const int t = threadIdx.x;
    const int l = t >> 6;       // wave-uniform
    const int rbeg = row_ptr[n];
    const int rend = row_ptr[n + 1];
    if (l == 0)      tp_node<0>(src_features, edge_sh, tp_u, es_list, out, n, t, rbeg, rend);
    else if (l == 1) tp_node<1>(src_features, edge_sh, tp_u, es_list, out, n, t, rbeg, rend);
    else if (l == 2) tp_node<2>(src_features, edge_sh, tp_u, es_list, out, n, t, rbeg, rend);
    else             tp_node<3>(src_features, edge_sh, tp_u, es_list, out, n, t, rbeg, rend);
}

// ---------------- launch ----------------

extern "C" void kernel_launch(void* const* d_in, const int* in_sizes, int n_in,
                              void* d_out, int out_size, void* d_ws, size_t ws_size,
                              hipStream_t stream) {
    const float* src_features = (const float*)d_in[0];
    const float* edge_sh      = (const float*)d_in[1];
    const float* edge_emb     = (const float*)d_in[2];
    const float* W1           = (const float*)d_in[3];
    const float* W2           = (const float*)d_in[4];
    const int*   src          = (const int*)d_in[5];
    const int*   dst          = (const int*)d_in[6];

    const int E     = in_sizes[5];
    const int N_DST = out_size / OUT_PER_NODE;
    const int EB    = (E + MT - 1) / MT;

    // ws layout (16B-aligned pieces first)
    char* p = (char*)d_ws;
    short* w1t      = (short*)p;              p += MIN_D * HID * 2;        // 16 KB
    short* w2t      = (short*)p;              p += HID * 512 * 2;          // 128 KB
    unsigned* tp_u  = (unsigned*)p;           p += (size_t)EB * MT * 1024; // ~100 MB
    int2* es_list   = (int2*)p;               p += (size_t)E * 8;
    int* counts     = (int*)p;                p += 16384 * 4;
    int* row_ptr    = (int*)p;                p += 16384 * 4;
    int* cursor     = (int*)p;                p += 16384 * 4;

    const int HB = (E + BLK - 1) / BLK;
    const int CB = (MIN_D * HID + HID * 512 + BLK - 1) / BLK;

    (void)hipMemsetAsync(counts, 0, (size_t)N_DST * 4, stream);
    prep_kernel<<<HB + CB, BLK, 0, stream>>>(dst, counts, E, W1, W2, w1t, w2t, HB);
    scan_kernel<<<1, SCAN_T, 0, stream>>>(counts, row_ptr, cursor, N_DST);
    scatter_kernel<<<(E + 255) / 256, 256, 0, stream>>>(dst, src, cursor, es_list, E);
    mlp_kernel<<<EB, MBLK, 0, stream>>>(edge_emb, w1t, w2t, tp_u, E);
    tp_kernel<<<N_DST, BLK, 0, stream>>>(src_features, edge_sh, tp_u,
                                         row_ptr, es_list, (float*)d_out);
}